// Round 7
// baseline (428.058 us; speedup 1.0000x reference)
//
#include <hip/hip_runtime.h>
#include <stdint.h>

#define NN 50000
#define EE 800000
#define NROWS 50048  // 782 * 64

typedef unsigned int u32;
typedef unsigned short u16;
using f32x4 = __attribute__((ext_vector_type(4))) float;
using short8 = __attribute__((ext_vector_type(8))) short;

__device__ __forceinline__ float bflo(u32 u) { return __uint_as_float(u << 16); }
__device__ __forceinline__ float bfhi(u32 u) { return __uint_as_float(u & 0xFFFF0000u); }
__device__ __forceinline__ float bf1(u16 v) { return __uint_as_float(((u32)v) << 16); }
__device__ __forceinline__ u32 f2bf(float f) {
    u32 u = __float_as_uint(f);
    return (u + 0x7FFFu + ((u >> 16) & 1u)) >> 16;
}
__device__ __forceinline__ u32 pack2(float lo, float hi) {
    return f2bf(lo) | (f2bf(hi) << 16);
}

// ---------- dtype detection: flag=1 if inputs are f32, 0 if bf16 ----------

__global__ void detect_kernel(const u32* __restrict__ xw, int* __restrict__ flag) {
    int tid = threadIdx.x;
    int cnt = 0;
    for (int i = tid; i < 8192; i += 256) {
        u32 u = xw[i];
        int e0 = (u >> 7) & 0xFF, e1 = (u >> 23) & 0xFF;
        cnt += (e0 >= 0xC3) + (e1 >= 0xC3);
    }
    #pragma unroll
    for (int off = 32; off; off >>= 1) cnt += __shfl_xor(cnt, off, 64);
    __shared__ int wsum[4];
    if ((tid & 63) == 0) wsum[tid >> 6] = cnt;
    __syncthreads();
    if (tid == 0) flag[0] = (wsum[0] + wsum[1] + wsum[2] + wsum[3] > 100) ? 1 : 0;
}

// ---------- degree / norm / CSR setup ----------

__global__ void count_deg_kernel(const int* __restrict__ ei, int* __restrict__ deg) {
    int e = blockIdx.x * 256 + threadIdx.x;
    if (e < EE) atomicAdd(&deg[ei[EE + e]], 1);
}

__global__ void scan1_kernel(const int* __restrict__ deg, int* __restrict__ excl,
                             int* __restrict__ bsum, float* __restrict__ dinv) {
    int i = blockIdx.x * 256 + threadIdx.x;
    int lane = threadIdx.x & 63, w = threadIdx.x >> 6;
    int v = (i < NN) ? deg[i] : 0;
    if (i < NN) dinv[i] = v > 0 ? rsqrtf((float)v) : 0.f;
    int x = v;
    #pragma unroll
    for (int off = 1; off < 64; off <<= 1) {
        int y = __shfl_up(x, off, 64);
        if (lane >= off) x += y;
    }
    __shared__ int ws[4];
    if (lane == 63) ws[w] = x;
    __syncthreads();
    int add = 0;
    if (w > 0) add += ws[0];
    if (w > 1) add += ws[1];
    if (w > 2) add += ws[2];
    if (i < NN) excl[i] = x - v + add;
    if (threadIdx.x == 255) bsum[blockIdx.x] = x + add;
}

__global__ void scan2_kernel(int* __restrict__ bsum, int* __restrict__ boff, int nb) {
    int tid = threadIdx.x, lane = tid & 63, w = tid >> 6;
    int v = (tid < nb) ? bsum[tid] : 0;
    int x = v;
    #pragma unroll
    for (int off = 1; off < 64; off <<= 1) {
        int y = __shfl_up(x, off, 64);
        if (lane >= off) x += y;
    }
    __shared__ int ws[4];
    if (lane == 63) ws[w] = x;
    __syncthreads();
    int add = 0;
    if (w > 0) add += ws[0];
    if (w > 1) add += ws[1];
    if (w > 2) add += ws[2];
    if (tid < nb) boff[tid] = x - v + add;
}

__global__ void scan3_kernel(int* __restrict__ rowptr, const int* __restrict__ boff,
                             int* __restrict__ woff) {
    int i = blockIdx.x * 256 + threadIdx.x;
    if (i < NN) {
        int r = rowptr[i] + boff[blockIdx.x];
        rowptr[i] = r;
        woff[i] = r;
    }
    if (i == 0) rowptr[NN] = EE;
}

// 4-byte edge record: just the source index (norm factored into dinv gathers)
__global__ void bucket_kernel(const int* __restrict__ ei, int* __restrict__ woff,
                              int* __restrict__ esrc) {
    int e = blockIdx.x * 256 + threadIdx.x;
    if (e >= EE) return;
    int r = ei[e], c = ei[EE + e];
    int p = atomicAdd(&woff[c], 1);
    esrc[p] = r;
}

// ---------- weight prep ----------
// mode 0: B[kk][col], kk = k*128+in; chunk J = (k*16 + in/8)*fout + o
// mode 1: B[in][c], c = k*fout+o (col-concat); J = (in/8)*(nk*fout) + k*fout + o
__global__ void wprep_kernel(const void* __restrict__ w, u16* __restrict__ wt,
                             int fout, int nk, int mode, int total,
                             const int* __restrict__ flag) {
    int idx = blockIdx.x * 256 + threadIdx.x;
    if (idx >= total) return;
    u16 v = flag[0] ? (u16)f2bf(((const float*)w)[idx]) : ((const u16*)w)[idx];
    int per = 128 * fout;
    int k = idx / per, rem = idx % per;
    int in = rem / fout, o = rem % fout;
    size_t J;
    if (mode == 0) J = (size_t)(k * 16 + (in >> 3)) * fout + o;
    else J = (size_t)(in >> 3) * (nk * fout) + k * fout + o;
    wt[J * 8 + (in & 7)] = v;
}

__global__ void bprep_kernel(const void* __restrict__ b1, const void* __restrict__ b2,
                             float* __restrict__ bf, const int* __restrict__ flag) {
    int i = threadIdx.x;  // 192 threads
    if (i < 128) bf[i] = flag[0] ? ((const float*)b1)[i] : bf1(((const u16*)b1)[i]);
    else {
        int j = i - 128;
        bf[i] = flag[0] ? ((const float*)b2)[j] : bf1(((const u16*)b2)[j]);
    }
}

// only needed when input is f32 (flag=1); bf16 input is used in place
__global__ void import_x_kernel(const void* __restrict__ x, u32* __restrict__ h,
                                const int* __restrict__ flag) {
    if (!flag[0]) return;
    int i = blockIdx.x * 256 + threadIdx.x;
    if (i >= NN * 64) return;
    const float* xf = (const float*)x;
    h[i] = pack2(xf[2 * i], xf[2 * i + 1]);
}

// ---------- prop 128-wide: one wave per node, 16-deep gather pipeline ----------
// out[c,:] = dinv[c] * sum_e dinv[src_e] * in[src_e,:]

__global__ __launch_bounds__(256) void prop128_kernel(const u32* __restrict__ hin,
                                                      const u32* __restrict__ halt,
                                                      u32* __restrict__ hout,
                                                      const int* __restrict__ rowptr,
                                                      const int* __restrict__ esrc,
                                                      const float* __restrict__ dinv,
                                                      const int* __restrict__ flag) {
    const u32* __restrict__ src = flag[0] ? halt : hin;
    int node = (blockIdx.x * 256 + threadIdx.x) >> 6;
    int lane = threadIdx.x & 63;
    if (node >= NN) return;
    int e0 = rowptr[node], e1 = rowptr[node + 1];
    float ax = 0.f, ay = 0.f;
    for (int base = e0; base < e1; base += 64) {
        int s_l = 0;
        float d_l = 0.f;
        if (base + lane < e1) {
            s_l = esrc[base + lane];
            d_l = dinv[s_l];
        }
        int cnt = e1 - base;
        if (cnt > 64) cnt = 64;
        for (int j = 0; j < cnt; j += 16) {
            u32 hv[16];
            float wg[16];
            #pragma unroll
            for (int u = 0; u < 16; u++) {
                int s = __builtin_amdgcn_readlane(s_l, j + u);
                wg[u] = __uint_as_float((u32)__builtin_amdgcn_readlane(
                    __float_as_int(d_l), j + u));
                hv[u] = src[(size_t)s * 64 + lane];
            }
            #pragma unroll
            for (int u = 0; u < 16; u++) {
                ax = fmaf(wg[u], bflo(hv[u]), ax);
                ay = fmaf(wg[u], bfhi(hv[u]), ay);
            }
        }
    }
    float dc = dinv[node];
    hout[(size_t)node * 64 + lane] = pack2(ax * dc, ay * dc);
}

// ---------- prop 64-wide (Horner): out = addend + A*in; FINAL adds bias+log_softmax ----------

__device__ __forceinline__ float gather64(const u16* __restrict__ hin, int e0, int e1,
                                          int lane, const int* __restrict__ esrc,
                                          const float* __restrict__ dinv) {
    float a = 0.f;
    for (int base = e0; base < e1; base += 64) {
        int s_l = 0;
        float d_l = 0.f;
        if (base + lane < e1) {
            s_l = esrc[base + lane];
            d_l = dinv[s_l];
        }
        int cnt = e1 - base;
        if (cnt > 64) cnt = 64;
        for (int j = 0; j < cnt; j += 16) {
            float hv[16], wg[16];
            #pragma unroll
            for (int u = 0; u < 16; u++) {
                int s = __builtin_amdgcn_readlane(s_l, j + u);
                wg[u] = __uint_as_float((u32)__builtin_amdgcn_readlane(
                    __float_as_int(d_l), j + u));
                hv[u] = bf1(hin[(size_t)s * 64 + lane]);
            }
            #pragma unroll
            for (int u = 0; u < 16; u++) a = fmaf(wg[u], hv[u], a);
        }
    }
    return a;
}

__global__ __launch_bounds__(256) void prop64_add_kernel(const u16* __restrict__ hin,
                                                         const u16* __restrict__ addend,
                                                         u16* __restrict__ hout,
                                                         const int* __restrict__ rowptr,
                                                         const int* __restrict__ esrc,
                                                         const float* __restrict__ dinv) {
    int node = (blockIdx.x * 256 + threadIdx.x) >> 6;
    int lane = threadIdx.x & 63;
    if (node >= NN) return;
    float a = gather64(hin, rowptr[node], rowptr[node + 1], lane, esrc, dinv);
    a = fmaf(a, dinv[node], bf1(addend[(size_t)node * 64 + lane]));
    hout[(size_t)node * 64 + lane] = (u16)f2bf(a);
}

__global__ __launch_bounds__(256) void prop64_final_kernel(const u16* __restrict__ hin,
                                                           const u16* __restrict__ z0,
                                                           const float* __restrict__ bias,
                                                           void* __restrict__ outv,
                                                           const int* __restrict__ rowptr,
                                                           const int* __restrict__ esrc,
                                                           const float* __restrict__ dinv,
                                                           const int* __restrict__ flag) {
    int node = (blockIdx.x * 256 + threadIdx.x) >> 6;
    int lane = threadIdx.x & 63;
    if (node >= NN) return;
    float v = gather64(hin, rowptr[node], rowptr[node + 1], lane, esrc, dinv);
    v = fmaf(v, dinv[node], bf1(z0[(size_t)node * 64 + lane]) + bias[lane]);
    float m = v;
    #pragma unroll
    for (int off = 32; off; off >>= 1) m = fmaxf(m, __shfl_xor(m, off, 64));
    float e = __expf(v - m);
    float s = e;
    #pragma unroll
    for (int off = 32; off; off >>= 1) s += __shfl_xor(s, off, 64);
    float r = v - m - __logf(s);
    if (flag[0]) ((float*)outv)[(size_t)node * 64 + lane] = r;
    else ((u16*)outv)[(size_t)node * 64 + lane] = (u16)f2bf(r);
}

// ---------- MFMA GEMM: LDS-staged A (XOR-swizzled), B chunks [k8][col] ----------

__device__ __forceinline__ short8 ld8(const u16* p) {
    return __builtin_bit_cast(short8, *(const uint4*)p);
}

// MODE 0: out = relu(A@B + bias) -> bf16 linear [N,128] into outH
//         (a0 selected by flag: a0 if flag=0 else a0alt; out must not alias
//          other blocks' reads — all a-reads are block-local rows, so OK)
// MODE 1: out -> 4 bf16 planes [N,64], plane = blockIdx.y (col-concat B)
template <int NHOP, int NT, int MODE>
__global__ __launch_bounds__(256) void gemm_kernel(const u32* __restrict__ a0,
                                                   const u32* __restrict__ a0alt,
                                                   const u32* __restrict__ a1,
                                                   const u32* __restrict__ a2,
                                                   const u32* __restrict__ a3,
                                                   const u16* __restrict__ wt, int ncol,
                                                   const float* __restrict__ bias,
                                                   u32* __restrict__ outH,
                                                   u16* __restrict__ zp0, u16* __restrict__ zp1,
                                                   u16* __restrict__ zp2, u16* __restrict__ zp3,
                                                   const int* __restrict__ flag) {
    __shared__ uint4 hs[1024];  // 64 rows x 16 chunks, XOR-swizzled
    const u32* A0 = flag[0] ? a0alt : a0;
    const u32* bufs[4] = {A0, a1, a2, a3};
    int t = threadIdx.x;
    int lane = t & 63, w = t >> 6;
    int row0 = blockIdx.x * 64;
    int cb = blockIdx.y * 16 * NT;
    int m = lane & 15, qo = lane >> 4;
    f32x4 acc[NT];
    #pragma unroll
    for (int tt = 0; tt < NT; tt++) acc[tt] = (f32x4){0.f, 0.f, 0.f, 0.f};

    uint4 p[4];
    {
        const uint4* src = (const uint4*)A0 + (size_t)row0 * 16;
        #pragma unroll
        for (int i = 0; i < 4; i++) p[i] = src[t + 256 * i];
    }
    #pragma unroll
    for (int hop = 0; hop < NHOP; hop++) {
        __syncthreads();
        #pragma unroll
        for (int i = 0; i < 4; i++) {
            int g = t + 256 * i;
            hs[(g >> 4) * 16 + ((g & 15) ^ ((g >> 4) & 15))] = p[i];
        }
        __syncthreads();
        if (hop + 1 < NHOP) {
            const uint4* src = (const uint4*)bufs[hop + 1] + (size_t)row0 * 16;
            #pragma unroll
            for (int i = 0; i < 4; i++) p[i] = src[t + 256 * i];
        }
        #pragma unroll
        for (int q = 0; q < 4; q++) {
            short8 a = __builtin_bit_cast(short8,
                hs[(16 * w + m) * 16 + ((q * 4 + qo) ^ m)]);
            short8 b[NT];
            #pragma unroll
            for (int tt = 0; tt < NT; tt++)
                b[tt] = ld8(wt + ((size_t)(hop * 16 + q * 4 + qo) * ncol + cb + 16 * tt + m) * 8);
            #pragma unroll
            for (int tt = 0; tt < NT; tt++)
                acc[tt] = __builtin_amdgcn_mfma_f32_16x16x32_bf16(a, b[tt], acc[tt], 0, 0, 0);
        }
    }

    int r0 = row0 + 16 * w + qo * 4;
    if (MODE == 0) {
        u16* o = (u16*)outH;
        #pragma unroll
        for (int tt = 0; tt < NT; tt++) {
            float bs = bias[cb + 16 * tt + m];
            #pragma unroll
            for (int r = 0; r < 4; r++) {
                int rr = r0 + r;
                if (rr < NN)
                    o[(size_t)rr * 128 + cb + 16 * tt + m] =
                        (u16)f2bf(fmaxf(acc[tt][r] + bs, 0.f));
            }
        }
    } else {
        u16* zp = (blockIdx.y == 0) ? zp0 : (blockIdx.y == 1) ? zp1
                  : (blockIdx.y == 2) ? zp2 : zp3;
        #pragma unroll
        for (int tt = 0; tt < NT; tt++) {
            #pragma unroll
            for (int r = 0; r < 4; r++) {
                int rr = r0 + r;
                if (rr < NN)
                    zp[(size_t)rr * 64 + 16 * tt + m] = (u16)f2bf(acc[tt][r]);
            }
        }
    }
}

// ---------- launch ----------

extern "C" void kernel_launch(void* const* d_in, const int* in_sizes, int n_in,
                              void* d_out, int out_size, void* d_ws, size_t ws_size,
                              hipStream_t stream) {
    const void* x  = d_in[0];
    const int*  ei = (const int*)d_in[1];
    const void* W1 = d_in[2];
    const void* b1 = d_in[3];
    const void* W2 = d_in[4];
    const void* b2 = d_in[5];

    char* ws = (char*)d_ws;
    size_t p = 0;
    auto alloc = [&](size_t bytes) -> void* {
        void* r = ws + p;
        p = (p + bytes + 255) & ~(size_t)255;
        return r;
    };
    int*   flag   = (int*)  alloc(256);
    int*   deg    = (int*)  alloc((size_t)NN * 4);
    float* dinv   = (float*)alloc((size_t)NN * 4);
    int*   rowptr = (int*)  alloc((size_t)(NN + 1) * 4);
    int*   woff   = (int*)  alloc((size_t)NN * 4);
    int*   bsum   = (int*)  alloc(256 * 4);
    int*   boff   = (int*)  alloc(256 * 4);
    int*   esrc   = (int*)  alloc((size_t)EE * 4);
    u16*   wt1    = (u16*)  alloc((size_t)64 * 128 * 16);   // 128 KB
    u16*   wt2    = (u16*)  alloc((size_t)16 * 256 * 16);   // 64 KB
    float* biasF  = (float*)alloc(192 * 4);
    const size_t hbytes = (size_t)(NROWS + 16) * 64 * 4;
    u32* hA = (u32*)alloc(hbytes);
    u32* hB = (u32*)alloc(hbytes);
    u32* hC = (u32*)alloc(hbytes);
    u32* hD = (u32*)alloc(hbytes);
    // ~55.5 MB total
    const size_t ZP = (size_t)(NROWS + 16) * 64;  // u16 elements per plane
    u16* z0 = (u16*)hB;
    u16* z1 = (u16*)hB + ZP;
    u16* z2 = (u16*)hC;
    u16* z3 = (u16*)hC + ZP;
    u16* t1 = (u16*)hD;
    u16* t2 = (u16*)hD + ZP;

    const int NB = (NN + 255) / 256;  // 196

    hipMemsetAsync(deg, 0, (size_t)NN * 4, stream);
    detect_kernel<<<1, 256, 0, stream>>>((const u32*)x, flag);
    count_deg_kernel<<<(EE + 255) / 256, 256, 0, stream>>>(ei, deg);
    scan1_kernel<<<NB, 256, 0, stream>>>(deg, rowptr, bsum, dinv);
    scan2_kernel<<<1, 256, 0, stream>>>(bsum, boff, NB);
    scan3_kernel<<<NB, 256, 0, stream>>>(rowptr, boff, woff);
    bucket_kernel<<<(EE + 255) / 256, 256, 0, stream>>>(ei, woff, esrc);
    wprep_kernel<<<(4 * 128 * 128 + 255) / 256, 256, 0, stream>>>(
        W1, wt1, 128, 4, 0, 4 * 128 * 128, flag);
    wprep_kernel<<<(4 * 128 * 64 + 255) / 256, 256, 0, stream>>>(
        W2, wt2, 64, 4, 1, 4 * 128 * 64, flag);
    bprep_kernel<<<1, 192, 0, stream>>>(b1, b2, biasF, flag);

    const int PG = (NN * 64) / 256;  // 12500: one wave per node
    const int GG = NROWS / 64;       // 782

    // builds hA only when flag=1 (f32 input); bf16 input used in place
    import_x_kernel<<<PG, 256, 0, stream>>>(x, hA, flag);

    // layer 1: h_k = A^k x (k=0..3), fused K=512 GEMM + bias + relu -> hA
    prop128_kernel<<<PG, 256, 0, stream>>>((const u32*)x, hA, hB, rowptr, esrc, dinv, flag);
    prop128_kernel<<<PG, 256, 0, stream>>>(hB, hB, hC, rowptr, esrc, dinv, flag);
    prop128_kernel<<<PG, 256, 0, stream>>>(hC, hC, hD, rowptr, esrc, dinv, flag);
    gemm_kernel<4, 8, 0><<<dim3(GG, 1), 256, 0, stream>>>(
        (const u32*)x, hA, hB, hC, hD, wt1, 128, biasF, hA,
        nullptr, nullptr, nullptr, nullptr, flag);

    // layer 2: Z = H @ [W2_0|W2_1|W2_2|W2_3]  (planes into hB, hC)
    gemm_kernel<1, 4, 1><<<dim3(GG, 4), 256, 0, stream>>>(
        hA, hA, hA, hA, hA, wt2, 256, biasF, nullptr, z0, z1, z2, z3, flag);

    // Horner: out = Z0 + A(Z1 + A(Z2 + A Z3)) + b2, then log_softmax
    prop64_add_kernel<<<PG, 256, 0, stream>>>(z3, z2, t1, rowptr, esrc, dinv);
    prop64_add_kernel<<<PG, 256, 0, stream>>>(t1, z1, t2, rowptr, esrc, dinv);
    prop64_final_kernel<<<PG, 256, 0, stream>>>(t2, z0, biasF + 128, d_out,
                                                rowptr, esrc, dinv, flag);
}

// Round 8
// 337.540 us; speedup vs baseline: 1.2682x; 1.2682x over previous
//
#include <hip/hip_runtime.h>
#include <stdint.h>

#define NN 50000
#define EE 800000
#define NROWS 50048  // 782 * 64
#define CB 196       // coarse buckets = ceil(NN/256)
#define CAP 5120     // padded capacity per coarse bucket (mean 4082, std ~64)
#define ACH 4096     // edges per phase-A block

typedef unsigned int u32;
typedef unsigned short u16;
using f32x4 = __attribute__((ext_vector_type(4))) float;
using short8 = __attribute__((ext_vector_type(8))) short;

__device__ __forceinline__ float bflo(u32 u) { return __uint_as_float(u << 16); }
__device__ __forceinline__ float bfhi(u32 u) { return __uint_as_float(u & 0xFFFF0000u); }
__device__ __forceinline__ float bf1(u16 v) { return __uint_as_float(((u32)v) << 16); }
__device__ __forceinline__ u32 f2bf(float f) {
    u32 u = __float_as_uint(f);
    return (u + 0x7FFFu + ((u >> 16) & 1u)) >> 16;
}
__device__ __forceinline__ u32 pack2(float lo, float hi) {
    return f2bf(lo) | (f2bf(hi) << 16);
}

// exclusive scan over 256 threads (one value each)
__device__ __forceinline__ int excl_scan256(int v, int tid) {
    __shared__ int ws_[4];
    int lane = tid & 63, w = tid >> 6;
    int x = v;
    #pragma unroll
    for (int off = 1; off < 64; off <<= 1) {
        int y = __shfl_up(x, off, 64);
        if (lane >= off) x += y;
    }
    if (lane == 63) ws_[w] = x;
    __syncthreads();
    int add = 0;
    if (w > 0) add += ws_[0];
    if (w > 1) add += ws_[1];
    if (w > 2) add += ws_[2];
    return add + x - v;
}

// ---------- dtype detection: flag=1 if inputs are f32, 0 if bf16 ----------

__global__ void detect_kernel(const u32* __restrict__ xw, int* __restrict__ flag) {
    int tid = threadIdx.x;
    int cnt = 0;
    for (int i = tid; i < 8192; i += 256) {
        u32 u = xw[i];
        int e0 = (u >> 7) & 0xFF, e1 = (u >> 23) & 0xFF;
        cnt += (e0 >= 0xC3) + (e1 >= 0xC3);
    }
    #pragma unroll
    for (int off = 32; off; off >>= 1) cnt += __shfl_xor(cnt, off, 64);
    __shared__ int wsum[4];
    if ((tid & 63) == 0) wsum[tid >> 6] = cnt;
    __syncthreads();
    if (tid == 0) flag[0] = (wsum[0] + wsum[1] + wsum[2] + wsum[3] > 100) ? 1 : 0;
}

// ---------- phase A: coarse counting sort by col>>8, clustered writes ----------

__global__ __launch_bounds__(256) void phaseA_kernel(const int* __restrict__ ei,
                                                     int* __restrict__ ccnt,
                                                     u32* __restrict__ cpad) {
    __shared__ int hist[256], lstart[256], lofs[256], gbase[256];
    __shared__ u32 srt[ACH];
    int tid = threadIdx.x;
    int e0 = blockIdx.x * ACH;
    int nv = EE - e0; if (nv > ACH) nv = ACH;
    hist[tid] = 0;
    __syncthreads();
    u32 pk[16];
    int bn[16];
    #pragma unroll
    for (int i = 0; i < 16; i++) {
        int e = e0 + tid + i * 256;
        bn[i] = -1;
        if (e < EE) {
            int r = ei[e], c = ei[EE + e];
            bn[i] = c >> 8;
            pk[i] = (u32)r | ((u32)(c & 255) << 16) | ((u32)bn[i] << 24);
            atomicAdd(&hist[bn[i]], 1);
        }
    }
    __syncthreads();
    int v = hist[tid];
    int excl = excl_scan256(v, tid);
    lstart[tid] = excl;
    lofs[tid] = excl;
    gbase[tid] = atomicAdd(&ccnt[tid], v);
    __syncthreads();
    #pragma unroll
    for (int i = 0; i < 16; i++)
        if (bn[i] >= 0) {
            int lp = atomicAdd(&lofs[bn[i]], 1);
            srt[lp] = pk[i];
        }
    __syncthreads();
    for (int j = tid; j < nv; j += 256) {
        u32 pv = srt[j];
        int b = pv >> 24;
        cpad[(size_t)b * CAP + gbase[b] + (j - lstart[b])] = pv;
    }
}

// exclusive scan of coarse counts -> cbase; sentinels
__global__ void cscan_kernel(const int* __restrict__ ccnt, int* __restrict__ cbase,
                             int* __restrict__ rowptr, float* __restrict__ dinv) {
    int tid = threadIdx.x;
    int v = ccnt[tid];
    int excl = excl_scan256(v, tid);
    cbase[tid] = excl;
    if (tid == 0) {
        rowptr[NN] = EE;
        rowptr[NN + 1] = EE;
        dinv[NN] = 0.f;
    }
}

// ---------- phase B: exact sort within coarse bucket; emits CSR + dinv + rinv ----------

__global__ __launch_bounds__(256) void phaseB_kernel(const u32* __restrict__ cpad,
                                                     const int* __restrict__ ccnt,
                                                     const int* __restrict__ cbase,
                                                     u16* __restrict__ esrc,
                                                     int* __restrict__ rowptr,
                                                     float* __restrict__ dinv,
                                                     float* __restrict__ rinv) {
    __shared__ int hist[256], lstart[256], lofs[256];
    __shared__ u16 srt[CAP];
    int tid = threadIdx.x, cb = blockIdx.x;
    int cnt = ccnt[cb], base = cbase[cb];
    hist[tid] = 0;
    __syncthreads();
    for (int j = tid; j < cnt; j += 256)
        atomicAdd(&hist[(cpad[(size_t)cb * CAP + j] >> 16) & 255], 1);
    __syncthreads();
    int v = hist[tid];
    int excl = excl_scan256(v, tid);
    lstart[tid] = excl;
    lofs[tid] = excl;
    int g = cb * 256 + tid;
    if (g < NN) {
        rowptr[g] = base + excl;
        dinv[g] = v > 0 ? rsqrtf((float)v) : 0.f;
        rinv[g] = v > 0 ? sqrtf((float)v) : 0.f;
    }
    __syncthreads();
    for (int j = tid; j < cnt; j += 256) {
        u32 pv = cpad[(size_t)cb * CAP + j];
        int lp = atomicAdd(&lofs[(pv >> 16) & 255], 1);
        srt[lp] = (u16)(pv & 0xFFFF);
    }
    __syncthreads();
    for (int j = tid; j < cnt; j += 256) esrc[base + j] = srt[j];
}

// ---------- weight prep ----------
// mode 0: chunk J = (k*16 + in/8)*fout + o       (K-concat, ncol=fout)
// mode 1: chunk J = (in/8)*(nk*fout) + k*fout + o (col-concat, ncol=nk*fout)
__global__ void wprep_kernel(const void* __restrict__ w, u16* __restrict__ wt,
                             int fout, int nk, int mode, int total,
                             const int* __restrict__ flag) {
    int idx = blockIdx.x * 256 + threadIdx.x;
    if (idx >= total) return;
    u16 v = flag[0] ? (u16)f2bf(((const float*)w)[idx]) : ((const u16*)w)[idx];
    int per = 128 * fout;
    int k = idx / per, rem = idx % per;
    int in = rem / fout, o = rem % fout;
    size_t J;
    if (mode == 0) J = (size_t)(k * 16 + (in >> 3)) * fout + o;
    else J = (size_t)(in >> 3) * (nk * fout) + k * fout + o;
    wt[J * 8 + (in & 7)] = v;
}

__global__ void bprep_kernel(const void* __restrict__ b1, const void* __restrict__ b2,
                             float* __restrict__ bf, const int* __restrict__ flag) {
    int i = threadIdx.x;  // 192 threads
    if (i < 128) bf[i] = flag[0] ? ((const float*)b1)[i] : bf1(((const u16*)b1)[i]);
    else {
        int j = i - 128;
        bf[i] = flag[0] ? ((const float*)b2)[j] : bf1(((const u16*)b2)[j]);
    }
}

// ---------- scale_x: g0 = dinv .* x (bf16); xb = bf16(x) when f32; zero row NN ----------

__global__ void scalex_kernel(const void* __restrict__ x, u32* __restrict__ g0,
                              u32* __restrict__ xb, const float* __restrict__ dinv,
                              const int* __restrict__ flag) {
    int i = blockIdx.x * 256 + threadIdx.x;
    if (i >= (NN + 1) * 64) return;
    int node = i >> 6;
    int fl = flag[0];
    if (node == NN) {
        g0[i] = 0;
        if (fl) xb[i] = 0;
        return;
    }
    float dv = dinv[node];
    float a, b;
    if (fl) {
        const float* xf = (const float*)x;
        a = xf[2 * i];
        b = xf[2 * i + 1];
        xb[i] = pack2(a, b);
    } else {
        u32 u = ((const u32*)x)[i];
        a = bflo(u);
        b = bfhi(u);
    }
    g0[i] = pack2(a * dv, b * dv);
}

// ---------- propg: g_{k+1} = dinv^2 .* S(g_k), unweighted gather, 128-wide ----------

__global__ __launch_bounds__(256) void propg_kernel(const u32* __restrict__ gin,
                                                    u32* __restrict__ gout,
                                                    const int* __restrict__ rowptr,
                                                    const u16* __restrict__ esrc,
                                                    const float* __restrict__ dinv) {
    int node = (blockIdx.x * 256 + threadIdx.x) >> 6;
    int lane = threadIdx.x & 63;
    if (node > NN) return;
    int e0 = rowptr[node], e1 = rowptr[node + 1];
    float ax = 0.f, ay = 0.f;
    for (int base = e0; base < e1; base += 64) {
        int s_l = NN;  // zero row
        if (base + lane < e1) s_l = esrc[base + lane];
        int cnt = e1 - base;
        if (cnt > 64) cnt = 64;
        for (int j = 0; j < cnt; j += 16) {
            u32 hv[16];
            #pragma unroll
            for (int u = 0; u < 16; u++) {
                int s = __builtin_amdgcn_readlane(s_l, j + u);
                hv[u] = gin[(size_t)s * 64 + lane];
            }
            #pragma unroll
            for (int u = 0; u < 16; u++) {
                ax += bflo(hv[u]);
                ay += bfhi(hv[u]);
            }
        }
    }
    float d = dinv[node];
    float d2 = d * d;
    gout[(size_t)node * 64 + lane] = pack2(ax * d2, ay * d2);
}

// ---------- prop64 (Horner, scaled domain): u_out = dinv.*z + dinv^2.*S(u_in) ----------

__device__ __forceinline__ float gatheru(const u16* __restrict__ uin, int e0, int e1,
                                         int lane, const u16* __restrict__ esrc) {
    float a = 0.f;
    for (int base = e0; base < e1; base += 64) {
        int s_l = NN;
        if (base + lane < e1) s_l = esrc[base + lane];
        int cnt = e1 - base;
        if (cnt > 64) cnt = 64;
        for (int j = 0; j < cnt; j += 16) {
            float hv[16];
            #pragma unroll
            for (int u = 0; u < 16; u++) {
                int s = __builtin_amdgcn_readlane(s_l, j + u);
                hv[u] = bf1(uin[(size_t)s * 64 + lane]);
            }
            #pragma unroll
            for (int u = 0; u < 16; u++) a += hv[u];
        }
    }
    return a;
}

__global__ __launch_bounds__(256) void prop64_add_kernel(const u16* __restrict__ uin,
                                                         const u16* __restrict__ zadd,
                                                         u16* __restrict__ uout,
                                                         const int* __restrict__ rowptr,
                                                         const u16* __restrict__ esrc,
                                                         const float* __restrict__ dinv) {
    int node = (blockIdx.x * 256 + threadIdx.x) >> 6;
    int lane = threadIdx.x & 63;
    if (node > NN) return;
    float s = gatheru(uin, rowptr[node], rowptr[node + 1], lane, esrc);
    float d = dinv[node];
    float r = fmaf(d * d, s, d * bf1(zadd[(size_t)node * 64 + lane]));
    uout[(size_t)node * 64 + lane] = (u16)f2bf(r);
}

__global__ __launch_bounds__(256) void prop64_final_kernel(const u16* __restrict__ uin,
                                                           const u16* __restrict__ z0,
                                                           const float* __restrict__ bias,
                                                           void* __restrict__ outv,
                                                           const int* __restrict__ rowptr,
                                                           const u16* __restrict__ esrc,
                                                           const float* __restrict__ dinv,
                                                           const int* __restrict__ flag) {
    int node = (blockIdx.x * 256 + threadIdx.x) >> 6;
    int lane = threadIdx.x & 63;
    if (node >= NN) return;
    float sg = gatheru(uin, rowptr[node], rowptr[node + 1], lane, esrc);
    float v = dinv[node] * sg + bf1(z0[(size_t)node * 64 + lane]) + bias[lane];
    float m = v;
    #pragma unroll
    for (int off = 32; off; off >>= 1) m = fmaxf(m, __shfl_xor(m, off, 64));
    float e = __expf(v - m);
    float s = e;
    #pragma unroll
    for (int off = 32; off; off >>= 1) s += __shfl_xor(s, off, 64);
    float r = v - m - __logf(s);
    if (flag[0]) ((float*)outv)[(size_t)node * 64 + lane] = r;
    else ((u16*)outv)[(size_t)node * 64 + lane] = (u16)f2bf(r);
}

// ---------- MFMA GEMMs ----------

__device__ __forceinline__ short8 ld8(const u16* p) {
    return __builtin_bit_cast(short8, *(const uint4*)p);
}

// layer 1: out = relu(x@W0 + rinv[row]*(g1@W1+g2@W2+g3@W3) + bias) -> bf16 [N,128]
__global__ __launch_bounds__(256) void gemm1_kernel(const u32* __restrict__ a0,
                                                    const u32* __restrict__ a0alt,
                                                    const u32* __restrict__ a1,
                                                    const u32* __restrict__ a2,
                                                    const u32* __restrict__ a3,
                                                    const u16* __restrict__ wt,
                                                    const float* __restrict__ rinv,
                                                    const float* __restrict__ bias,
                                                    u32* __restrict__ outH,
                                                    const int* __restrict__ flag) {
    __shared__ uint4 hs[1024];
    const u32* A0 = flag[0] ? a0alt : a0;
    const u32* bufs[4] = {A0, a1, a2, a3};
    int t = threadIdx.x;
    int lane = t & 63, w = t >> 6;
    int row0 = blockIdx.x * 64;
    int m = lane & 15, qo = lane >> 4;
    f32x4 accx[8], accg[8];
    #pragma unroll
    for (int tt = 0; tt < 8; tt++) {
        accx[tt] = (f32x4){0.f, 0.f, 0.f, 0.f};
        accg[tt] = (f32x4){0.f, 0.f, 0.f, 0.f};
    }

    uint4 p[4];
    {
        const uint4* src = (const uint4*)A0 + (size_t)row0 * 16;
        #pragma unroll
        for (int i = 0; i < 4; i++) p[i] = src[t + 256 * i];
    }
    #pragma unroll
    for (int hop = 0; hop < 4; hop++) {
        __syncthreads();
        #pragma unroll
        for (int i = 0; i < 4; i++) {
            int g = t + 256 * i;
            hs[(g >> 4) * 16 + ((g & 15) ^ ((g >> 4) & 15))] = p[i];
        }
        __syncthreads();
        if (hop + 1 < 4) {
            const uint4* src = (const uint4*)bufs[hop + 1] + (size_t)row0 * 16;
            #pragma unroll
            for (int i = 0; i < 4; i++) p[i] = src[t + 256 * i];
        }
        #pragma unroll
        for (int q = 0; q < 4; q++) {
            short8 a = __builtin_bit_cast(short8,
                hs[(16 * w + m) * 16 + ((q * 4 + qo) ^ m)]);
            short8 b[8];
            #pragma unroll
            for (int tt = 0; tt < 8; tt++)
                b[tt] = ld8(wt + ((size_t)(hop * 16 + q * 4 + qo) * 128 + 16 * tt + m) * 8);
            if (hop == 0) {
                #pragma unroll
                for (int tt = 0; tt < 8; tt++)
                    accx[tt] = __builtin_amdgcn_mfma_f32_16x16x32_bf16(a, b[tt], accx[tt], 0, 0, 0);
            } else {
                #pragma unroll
                for (int tt = 0; tt < 8; tt++)
                    accg[tt] = __builtin_amdgcn_mfma_f32_16x16x32_bf16(a, b[tt], accg[tt], 0, 0, 0);
            }
        }
    }

    int r0 = row0 + 16 * w + qo * 4;
    float rv[4];
    #pragma unroll
    for (int r = 0; r < 4; r++) rv[r] = (r0 + r < NN) ? rinv[r0 + r] : 0.f;
    u16* o = (u16*)outH;
    #pragma unroll
    for (int tt = 0; tt < 8; tt++) {
        float bs = bias[16 * tt + m];
        #pragma unroll
        for (int r = 0; r < 4; r++) {
            int rr = r0 + r;
            if (rr < NN) {
                float vv = accx[tt][r] + rv[r] * accg[tt][r] + bs;
                o[(size_t)rr * 128 + 16 * tt + m] = (u16)f2bf(fmaxf(vv, 0.f));
            }
        }
    }
}

// layer 2: Z planes = H @ [W2_0|W2_1|W2_2|W2_3]; plane 3 pre-scaled by dinv; row NN zeroed
__global__ __launch_bounds__(256) void gemmz_kernel(const u32* __restrict__ aH,
                                                    const u16* __restrict__ wt,
                                                    const float* __restrict__ dinv,
                                                    u16* __restrict__ p0, u16* __restrict__ p1,
                                                    u16* __restrict__ p2, u16* __restrict__ p3) {
    __shared__ uint4 hs[1024];
    int t = threadIdx.x;
    int lane = t & 63, w = t >> 6;
    int row0 = blockIdx.x * 64;
    int py = blockIdx.y;
    int cb = py * 64;
    int m = lane & 15, qo = lane >> 4;
    f32x4 acc[4];
    #pragma unroll
    for (int tt = 0; tt < 4; tt++) acc[tt] = (f32x4){0.f, 0.f, 0.f, 0.f};
    {
        const uint4* src = (const uint4*)aH + (size_t)row0 * 16;
        #pragma unroll
        for (int i = 0; i < 4; i++) {
            int g = t + 256 * i;
            hs[(g >> 4) * 16 + ((g & 15) ^ ((g >> 4) & 15))] = src[g];
        }
    }
    __syncthreads();
    #pragma unroll
    for (int q = 0; q < 4; q++) {
        short8 a = __builtin_bit_cast(short8,
            hs[(16 * w + m) * 16 + ((q * 4 + qo) ^ m)]);
        short8 b[4];
        #pragma unroll
        for (int tt = 0; tt < 4; tt++)
            b[tt] = ld8(wt + ((size_t)(q * 4 + qo) * 256 + cb + 16 * tt + m) * 8);
        #pragma unroll
        for (int tt = 0; tt < 4; tt++)
            acc[tt] = __builtin_amdgcn_mfma_f32_16x16x32_bf16(a, b[tt], acc[tt], 0, 0, 0);
    }
    u16* zp = (py == 0) ? p0 : (py == 1) ? p1 : (py == 2) ? p2 : p3;
    int r0 = row0 + 16 * w + qo * 4;
    #pragma unroll
    for (int r = 0; r < 4; r++) {
        int rr = r0 + r;
        float sc = 1.f;
        if (py == 3) sc = (rr < NN) ? dinv[rr] : 0.f;
        #pragma unroll
        for (int tt = 0; tt < 4; tt++) {
            u16 val = (rr < NN) ? (u16)f2bf(sc * acc[tt][r]) : (u16)0;
            zp[(size_t)rr * 64 + 16 * tt + m] = val;
        }
    }
}

// ---------- launch ----------

extern "C" void kernel_launch(void* const* d_in, const int* in_sizes, int n_in,
                              void* d_out, int out_size, void* d_ws, size_t ws_size,
                              hipStream_t stream) {
    const void* x  = d_in[0];
    const int*  ei = (const int*)d_in[1];
    const void* W1 = d_in[2];
    const void* b1 = d_in[3];
    const void* W2 = d_in[4];
    const void* b2 = d_in[5];

    char* ws = (char*)d_ws;
    size_t p = 0;
    auto alloc = [&](size_t bytes) -> void* {
        void* r = ws + p;
        p = (p + bytes + 255) & ~(size_t)255;
        return r;
    };
    int*   flag   = (int*)  alloc(256);
    int*   rowptr = (int*)  alloc((size_t)(NN + 2) * 4);
    float* dinv   = (float*)alloc((size_t)(NN + 64) * 4);
    float* rinv   = (float*)alloc((size_t)(NN + 64) * 4);
    int*   ccnt   = (int*)  alloc(256 * 4);
    int*   cbase  = (int*)  alloc(256 * 4);
    u16*   esrc   = (u16*)  alloc((size_t)EE * 2);
    u16*   wt1    = (u16*)  alloc((size_t)64 * 128 * 16);   // 128 KB
    u16*   wt2    = (u16*)  alloc((size_t)16 * 256 * 16);   // 64 KB
    float* biasF  = (float*)alloc(192 * 4);
    const size_t hbytes = (size_t)(NROWS + 16) * 64 * 4;
    u32* X = (u32*)alloc(hbytes);   // xb (flag=1); cpad aliases here (dead before scalex)
    u32* P = (u32*)alloc(hbytes);   // g0 -> g3 -> z2/u3 planes
    u32* Q = (u32*)alloc(hbytes);   // g1 -> H
    u32* R = (u32*)alloc(hbytes);   // g2 -> z0/z1 planes
    // total ~= 53.6 MB
    u32* cpad = X;

    const size_t ZP = (size_t)(NROWS + 16) * 64;  // u16 elements per plane
    u16* zR0 = (u16*)R;        // z0
    u16* zR1 = (u16*)R + ZP;   // z1
    u16* zP0 = (u16*)P;        // z2
    u16* zP1 = (u16*)P + ZP;   // u3 = dinv.*z3
    u16* uX0 = (u16*)X;        // u_w1
    // u_w2 goes to zP0 after z2 is consumed

    hipMemsetAsync(ccnt, 0, 256 * 4, stream);
    detect_kernel<<<1, 256, 0, stream>>>((const u32*)x, flag);
    phaseA_kernel<<<(EE + ACH - 1) / ACH, 256, 0, stream>>>(ei, ccnt, cpad);
    cscan_kernel<<<1, 256, 0, stream>>>(ccnt, cbase, rowptr, dinv);
    phaseB_kernel<<<CB, 256, 0, stream>>>(cpad, ccnt, cbase, esrc, rowptr, dinv, rinv);
    wprep_kernel<<<(4 * 128 * 128 + 255) / 256, 256, 0, stream>>>(
        W1, wt1, 128, 4, 0, 4 * 128 * 128, flag);
    wprep_kernel<<<(4 * 128 * 64 + 255) / 256, 256, 0, stream>>>(
        W2, wt2, 64, 4, 1, 4 * 128 * 64, flag);
    bprep_kernel<<<1, 192, 0, stream>>>(b1, b2, biasF, flag);

    const int PGX = ((NN + 1) * 64 + 255) / 256;  // 12501 (covers zero row NN)
    const int PGF = (NN * 64) / 256;              // 12500
    const int GG = NROWS / 64;                    // 782

    scalex_kernel<<<PGX, 256, 0, stream>>>(x, P, X, dinv, flag);

    // layer 1: g_k chain (unweighted gathers), then dual-acc GEMM + bias + relu -> H (=Q)
    propg_kernel<<<PGX, 256, 0, stream>>>(P, Q, rowptr, esrc, dinv);  // g1
    propg_kernel<<<PGX, 256, 0, stream>>>(Q, R, rowptr, esrc, dinv);  // g2
    propg_kernel<<<PGX, 256, 0, stream>>>(R, P, rowptr, esrc, dinv);  // g3 (g0 dead)
    gemm1_kernel<<<GG, 256, 0, stream>>>((const u32*)x, X, Q, R, P, wt1, rinv, biasF, Q, flag);

    // layer 2: Z planes from H; Horner in scaled domain; fused bias + log_softmax
    gemmz_kernel<<<dim3(GG, 4), 256, 0, stream>>>(Q, wt2, dinv, zR0, zR1, zP0, zP1);
    prop64_add_kernel<<<PGX, 256, 0, stream>>>(zP1, zP0, uX0, rowptr, esrc, dinv);  // u_w1
    prop64_add_kernel<<<PGX, 256, 0, stream>>>(uX0, zR1, zP0, rowptr, esrc, dinv);  // u_w2
    prop64_final_kernel<<<PGF, 256, 0, stream>>>(zP0, zR0, biasF + 128, d_out,
                                                 rowptr, esrc, dinv, flag);
}